// Round 2
// baseline (239977.686 us; speedup 1.0000x reference)
//
#include <hip/hip_runtime.h>

#define RS 1024   // reservoir
#define SL 4096   // seq len
#define NB 1024   // batch
#define NI 16     // input size
#define ROWS 16   // batch rows per WG
#define NWG (NB / ROWS)  // 64 workgroups

typedef short s8v __attribute__((ext_vector_type(8)));
typedef float f4v __attribute__((ext_vector_type(4)));

static __device__ __forceinline__ unsigned short f2bf(float f) {
  unsigned u = __float_as_uint(f);
  u += 0x7fffu + ((u >> 16) & 1u);          // round-to-nearest-even
  return (unsigned short)(u >> 16);
}
static __device__ __forceinline__ float bf2f(unsigned short b) {
  return __uint_as_float(((unsigned)b) << 16);
}
static __device__ __forceinline__ float fast_tanh(float a) {
  float e = __expf(2.0f * a);               // saturates correctly at +/-inf
  return 1.0f - 2.0f / (e + 1.0f);
}

// prep: W fp32 -> bf16 row-major (2 MB in ws)
__global__ __launch_bounds__(256) void prep_kernel(const float* __restrict__ W,
                                                   unsigned short* __restrict__ wbf) {
  int idx = blockIdx.x * 256 + threadIdx.x;
  if (idx < RS * RS) wbf[idx] = f2bf(W[idx]);
}

// Full-ownership recurrent kernel: WG b owns batch rows [16b,16b+16) and the
// ENTIRE 1024-dim recurrence for them. h lives in LDS only (double buffer,
// XOR-swizzled rows). W streams from L2 each step. Zero inter-WG traffic.
// Wave w owns reservoir cols [64w,64w+64) = 4 tiles of 16x16, K=1024.
__global__ __launch_bounds__(1024) void esn_kernel(
    const float* __restrict__ x, const float* __restrict__ Win,
    const unsigned short* __restrict__ wbf, const float* __restrict__ Wout,
    const float* __restrict__ bias, float* __restrict__ y) {
  extern __shared__ char smem[];
  char* bufA = smem;                 // 32 KB: h rows [16][1024] bf16, swizzled
  char* bufB = smem + ROWS * 2048;   // 32 KB

  const int bid = blockIdx.x;
  const int tid = threadIdx.x;
  const int w = tid >> 6;            // wave 0..15
  const int lane = tid & 63;
  const int l15 = lane & 15;
  const int lq = lane >> 4;          // k-quad 0..3
  const int m0 = bid * ROWS;         // batch row base
  const int n0w = w * 64;            // reservoir col base for this wave

  union U8 { s8v v; unsigned short u[8]; };

  // persistent Win fragments, hi/lo split for ~fp32 input projection:
  // MFMA1: [xhi|xlo] . [Whi|Whi] = x.Whi ; MFMA2: [xhi|0] . [Wlo|0] = xhi.Wlo
  U8 b1[4], b2[4];
#pragma unroll
  for (int nt = 0; nt < 4; nt++) {
    const int n = n0w + nt * 16 + l15;
    const float* p = Win + n * NI + (lq & 1) * 8;
#pragma unroll
    for (int i = 0; i < 8; i++) {
      float f = p[i];
      unsigned short hi = f2bf(f);
      b1[nt].u[i] = hi;
      b2[nt].u[i] = (lq < 2) ? f2bf(f - bf2f(hi)) : (unsigned short)0;
    }
  }

  // zero initial h (bufA)
  for (int i = tid; i < ROWS * 2048 / 16; i += 1024)
    ((uint4*)bufA)[i] = make_uint4(0u, 0u, 0u, 0u);
  __syncthreads();

  const int swz = (l15 & 7) << 4;    // row-XOR swizzle for A reads
  // W row pointers for the 4 n-tiles (include k-quad element offset)
  const unsigned short* wrow[4];
#pragma unroll
  for (int nt = 0; nt < 4; nt++)
    wrow[nt] = wbf + (size_t)(n0w + nt * 16 + l15) * RS + lq * 8;

  const float* xrow = x + (size_t)(m0 + l15) * SL * NI + (lq & 1) * 8;

  for (int t = 0; t < SL; t++) {
    const char* hc = (t & 1) ? bufB : bufA;
    char* hn = (t & 1) ? bufA : bufB;

    // issue x loads early; K-loop hides their HBM latency
    float xf[8];
    const float* xp = xrow + (size_t)t * NI;
#pragma unroll
    for (int i = 0; i < 8; i++) xf[i] = xp[i];

    f4v acc[4] = {{0,0,0,0},{0,0,0,0},{0,0,0,0},{0,0,0,0}};

    // main K loop: h[16 rows] @ W^T for 64 cols; A from LDS, B from L2
    const char* arow = hc + l15 * 2048;
#pragma unroll 8
    for (int kk = 0; kk < 32; kk++) {
      s8v av = *(const s8v*)(arow + ((kk * 64 + lq * 16) ^ swz));
#pragma unroll
      for (int nt = 0; nt < 4; nt++) {
        s8v bv = *(const s8v*)(wrow[nt] + kk * 32);
        acc[nt] = __builtin_amdgcn_mfma_f32_16x16x32_bf16(av, bv, acc[nt], 0, 0, 0);
      }
    }

    // input projection (x hi/lo split)
    U8 a1, a2;
#pragma unroll
    for (int i = 0; i < 8; i++) {
      float f = xf[i];
      unsigned short hi = f2bf(f);
      unsigned short lo = f2bf(f - bf2f(hi));
      a1.u[i] = (lq < 2) ? hi : lo;
      a2.u[i] = (lq < 2) ? hi : (unsigned short)0;
    }
#pragma unroll
    for (int nt = 0; nt < 4; nt++) {
      acc[nt] = __builtin_amdgcn_mfma_f32_16x16x32_bf16(a1.v, b1[nt].v, acc[nt], 0, 0, 0);
      acc[nt] = __builtin_amdgcn_mfma_f32_16x16x32_bf16(a2.v, b2[nt].v, acc[nt], 0, 0, 0);
    }

    // tanh + bf16 store to next LDS buffer.
    // C/D 16x16: col = lane&15, row = (lane>>4)*4 + r
#pragma unroll
    for (int nt = 0; nt < 4; nt++) {
      const int nb = (n0w + nt * 16 + l15) * 2;   // byte offset of col in row
#pragma unroll
      for (int r = 0; r < 4; r++) {
        const int mrow = lq * 4 + r;
        *(unsigned short*)(hn + mrow * 2048 + (nb ^ ((mrow & 7) << 4))) =
            f2bf(fast_tanh(acc[nt][r]));
      }
    }
    __syncthreads();
  }

  // fused output projection: final h (t=4095 wrote bufA): y = h @ Wout^T + b
  if (tid < 256) {
    const int r = tid >> 4, o = tid & 15;
    const char* hr = bufA + r * 2048;
    const int sw = (r & 7) << 4;
    const float* wr = Wout + o * RS;
    float s = bias[o];
    for (int k = 0; k < RS; k++)
      s += bf2f(*(const unsigned short*)(hr + ((2 * k) ^ sw))) * wr[k];
    y[(m0 + r) * NI + o] = s;
  }
}

extern "C" void kernel_launch(void* const* d_in, const int* in_sizes, int n_in,
                              void* d_out, int out_size, void* d_ws, size_t ws_size,
                              hipStream_t stream) {
  const float* x = (const float*)d_in[0];
  const float* Win = (const float*)d_in[1];
  const float* W = (const float*)d_in[2];
  const float* Wout = (const float*)d_in[3];
  const float* bias = (const float*)d_in[4];
  float* y = (float*)d_out;

  unsigned short* wbf = (unsigned short*)d_ws;   // 2 MB W bf16

  hipFuncSetAttribute((const void*)esn_kernel,
                      hipFuncAttributeMaxDynamicSharedMemorySize, 2 * ROWS * 2048);

  prep_kernel<<<(RS * RS + 255) / 256, 256, 0, stream>>>(W, wbf);
  esn_kernel<<<NWG, 1024, 2 * ROWS * 2048, stream>>>(x, Win, wbf, Wout, bias, y);
}

// Round 3
// 230139.160 us; speedup vs baseline: 1.0428x; 1.0428x over previous
//
#include <hip/hip_runtime.h>

#define RS 1024   // reservoir
#define SL 4096   // seq len
#define NB 1024   // batch
#define NI 16     // input size
#define ROWS 16   // batch rows per WG
#define NWG (NB / ROWS)  // 64 workgroups

typedef short s8v __attribute__((ext_vector_type(8)));
typedef float f4v __attribute__((ext_vector_type(4)));

static __device__ __forceinline__ unsigned short f2bf(float f) {
  unsigned u = __float_as_uint(f);
  u += 0x7fffu + ((u >> 16) & 1u);          // round-to-nearest-even
  return (unsigned short)(u >> 16);
}
static __device__ __forceinline__ float bf2f(unsigned short b) {
  return __uint_as_float(((unsigned)b) << 16);
}
static __device__ __forceinline__ float fast_tanh(float a) {
  float e = __expf(2.0f * a);               // saturates correctly at +/-inf
  return 1.0f - 2.0f / (e + 1.0f);
}

// prep: W fp32 -> bf16 row-major; Win -> hi/lo 16B MFMA fragments
// winA[n*4+lq][8] = Win_hi[n][oct(lq&1)] ; winB = lq<2 ? Win_lo[n][oct lq] : 0
__global__ __launch_bounds__(256) void prep_kernel(
    const float* __restrict__ W, const float* __restrict__ Win,
    unsigned short* __restrict__ wbf, unsigned short* __restrict__ winA,
    unsigned short* __restrict__ winB) {
  int idx = blockIdx.x * 256 + threadIdx.x;
  if (idx < RS * RS) wbf[idx] = f2bf(W[idx]);
  if (idx < RS * 4) {
    int n = idx >> 2, lq = idx & 3;
    const float* p = Win + n * NI + (lq & 1) * 8;
    unsigned short* a = winA + idx * 8;
    unsigned short* b = winB + idx * 8;
    for (int i = 0; i < 8; i++) {
      float f = p[i];
      unsigned short hi = f2bf(f);
      a[i] = hi;
      b[i] = (lq < 2) ? f2bf(f - bf2f(hi)) : (unsigned short)0;
    }
  }
}

// Full-ownership recurrence, pipelined: WG b owns batch rows [16b,16b+16).
// h in LDS (32 KB, in-place, XOR-swizzled). W streamed L2->regs with a
// depth-2 register double-buffer feeding 16x16x32 MFMAs. 16 waves/WG,
// wave w owns reservoir cols [64w,64w+64) as 4 n-tiles.
__global__ __launch_bounds__(1024) void esn_kernel(
    const float* __restrict__ x, const unsigned short* __restrict__ wbf,
    const unsigned short* __restrict__ winA, const unsigned short* __restrict__ winB,
    const float* __restrict__ Wout, const float* __restrict__ bias,
    float* __restrict__ y) {
  __shared__ char hsm[ROWS * 2048];   // h[16][1024] bf16, row-swizzled

  const int tid = threadIdx.x;
  const int w = tid >> 6;             // wave 0..15
  const int lane = tid & 63;
  const int l15 = lane & 15;
  const int lq = lane >> 4;           // k-octet 0..3
  const int m0 = blockIdx.x * ROWS;
  const int n0w = w << 6;

  // zero initial h
  for (int i = tid; i < ROWS * 2048 / 16; i += 1024)
    ((uint4*)hsm)[i] = make_uint4(0u, 0u, 0u, 0u);

  // persistent Win fragments (constant across steps)
  s8v b1[4], b2[4];
#pragma unroll
  for (int nt = 0; nt < 4; nt++) {
    const int fi = ((n0w + nt * 16 + l15) * 4 + lq) * 8;
    b1[nt] = *(const s8v*)(winA + fi);
    b2[nt] = *(const s8v*)(winB + fi);
  }

  // B-operand element offsets into wbf (SGPR base + 32-bit voffset form)
  int boff[4];
#pragma unroll
  for (int nt = 0; nt < 4; nt++) boff[nt] = (n0w + nt * 16 + l15) * RS + lq * 8;

  const float* xrow = x + (size_t)(m0 + l15) * SL * NI + (lq & 1) * 8;

  __syncthreads();

  // prime the pipeline: x(0), W k-groups 0 and 1
  float xf[8];
#pragma unroll
  for (int i = 0; i < 8; i++) xf[i] = xrow[i];
  s8v bA[4], bB[4];
#pragma unroll
  for (int nt = 0; nt < 4; nt++) {
    bA[nt] = *(const s8v*)(wbf + boff[nt]);
    bB[nt] = *(const s8v*)(wbf + boff[nt] + 32);
  }

  const char* hbase = hsm + l15 * 2048;
  const int swz = (l15 & 7) << 4;

  for (int t = 0; t < SL; t++) {
    // ---- input projection: acc = x_t @ Win^T (hi/lo split, 2 MFMAs) ----
    union U8 { s8v v; unsigned short u[8]; } a1, a2;
#pragma unroll
    for (int i = 0; i < 8; i++) {
      float f = xf[i];
      unsigned short hi = f2bf(f);
      a1.u[i] = (lq < 2) ? hi : f2bf(f - bf2f(hi));
      a2.u[i] = (lq < 2) ? hi : (unsigned short)0;
    }
    f4v acc[4];
#pragma unroll
    for (int nt = 0; nt < 4; nt++) {
      f4v z = {0.f, 0.f, 0.f, 0.f};
      z = __builtin_amdgcn_mfma_f32_16x16x32_bf16(a1.v, b1[nt], z, 0, 0, 0);
      z = __builtin_amdgcn_mfma_f32_16x16x32_bf16(a2.v, b2[nt], z, 0, 0, 0);
      acc[nt] = z;
    }

    // ---- K loop: h @ W^T, 32 k-steps, B depth-2 register pipeline ----
#pragma unroll
    for (int kk = 0; kk < 32; kk += 2) {
      s8v av0 = *(const s8v*)(hbase + ((kk * 64 + lq * 16) ^ swz));
#pragma unroll
      for (int nt = 0; nt < 4; nt++)
        acc[nt] = __builtin_amdgcn_mfma_f32_16x16x32_bf16(av0, bA[nt], acc[nt], 0, 0, 0);
      if (kk + 2 < 32) {
#pragma unroll
        for (int nt = 0; nt < 4; nt++)
          bA[nt] = *(const s8v*)(wbf + boff[nt] + (kk + 2) * 32);
      }
      s8v av1 = *(const s8v*)(hbase + (((kk + 1) * 64 + lq * 16) ^ swz));
#pragma unroll
      for (int nt = 0; nt < 4; nt++)
        acc[nt] = __builtin_amdgcn_mfma_f32_16x16x32_bf16(av1, bB[nt], acc[nt], 0, 0, 0);
      if (kk + 3 < 32) {
#pragma unroll
        for (int nt = 0; nt < 4; nt++)
          bB[nt] = *(const s8v*)(wbf + boff[nt] + (kk + 3) * 32);
      }
    }

    // ---- prefetch next step's W groups 0/1 and x while barriers drain ----
#pragma unroll
    for (int nt = 0; nt < 4; nt++) {
      bA[nt] = *(const s8v*)(wbf + boff[nt]);
      bB[nt] = *(const s8v*)(wbf + boff[nt] + 32);
    }
    {
      const float* xp = xrow + (size_t)((t + 1 < SL) ? t + 1 : 0) * NI;
#pragma unroll
      for (int i = 0; i < 8; i++) xf[i] = xp[i];
    }

    __syncthreads();   // all reads of h(t) complete
    // epilogue: tanh + write h(t+1) in place. C/D: col=l15, row=lq*4+r
#pragma unroll
    for (int nt = 0; nt < 4; nt++) {
      const int nb = (n0w + nt * 16 + l15) * 2;
#pragma unroll
      for (int r = 0; r < 4; r++) {
        const int m = lq * 4 + r;
        *(unsigned short*)(hsm + m * 2048 + (nb ^ ((m & 7) << 4))) =
            f2bf(fast_tanh(acc[nt][r]));
      }
    }
    __syncthreads();   // h(t+1) visible
  }

  // ---- fused output projection: y = h_final @ Wout^T + b ----
  if (tid < 256) {
    const int r = tid >> 4, o = tid & 15;
    const char* hr = hsm + r * 2048;
    const int sw = (r & 7) << 4;
    const float* wr = Wout + o * RS;
    float s = bias[o];
    for (int k = 0; k < RS; k++)
      s += bf2f(*(const unsigned short*)(hr + ((2 * k) ^ sw))) * wr[k];
    y[(m0 + r) * NI + o] = s;
  }
}

extern "C" void kernel_launch(void* const* d_in, const int* in_sizes, int n_in,
                              void* d_out, int out_size, void* d_ws, size_t ws_size,
                              hipStream_t stream) {
  const float* x = (const float*)d_in[0];
  const float* Win = (const float*)d_in[1];
  const float* W = (const float*)d_in[2];
  const float* Wout = (const float*)d_in[3];
  const float* bias = (const float*)d_in[4];
  float* y = (float*)d_out;

  char* ws = (char*)d_ws;
  unsigned short* wbf = (unsigned short*)ws;                       // 2 MB
  unsigned short* winA = (unsigned short*)(ws + (1 << 21));        // 64 KB
  unsigned short* winB = (unsigned short*)(ws + (1 << 21) + (1 << 16)); // 64 KB

  prep_kernel<<<(RS * RS + 255) / 256, 256, 0, stream>>>(W, Win, wbf, winA, winB);
  esn_kernel<<<NWG, 1024, 0, stream>>>(x, wbf, winA, winB, Wout, bias, y);
}

// Round 4
// 44426.102 us; speedup vs baseline: 5.4017x; 5.1803x over previous
//
#include <hip/hip_runtime.h>

#define RS 1024   // reservoir
#define SL 4096   // seq len
#define NB 1024   // batch
#define NI 16     // input size
#define RGRP 32   // batch rows per group
#define CWG 128   // reservoir cols per WG
#define WPG 8     // WGs per group (8 * 128 = 1024 cols)
#define NGRP 32   // groups (32 * 32 = 1024 rows)

typedef short s8v __attribute__((ext_vector_type(8)));
typedef float f4v __attribute__((ext_vector_type(4)));

static __device__ __forceinline__ unsigned short f2bf(float f) {
  unsigned u = __float_as_uint(f);
  u += 0x7fffu + ((u >> 16) & 1u);          // round-to-nearest-even
  return (unsigned short)(u >> 16);
}
static __device__ __forceinline__ float bf2f(unsigned short b) {
  return __uint_as_float(((unsigned)b) << 16);
}
static __device__ __forceinline__ float fast_tanh(float a) {
  float e = __expf(2.0f * a);               // saturates correctly at +/-inf
  return 1.0f - 2.0f / (e + 1.0f);
}

// prep: W fp32 -> bf16; zero h0 (buffer A); zero group flags
__global__ __launch_bounds__(256) void prep_kernel(
    const float* __restrict__ W, unsigned short* __restrict__ wbf,
    uint4* __restrict__ hA4, int* __restrict__ flags) {
  int idx = blockIdx.x * 256 + threadIdx.x;
  if (idx < RS * RS) wbf[idx] = f2bf(W[idx]);
  if (idx < (NB * RS) / 8) hA4[idx] = make_uint4(0u, 0u, 0u, 0u);
  if (idx < NGRP * 64) flags[idx] = 0;
}

// W-register-resident recurrence with h-exchange.
// 256 WGs x 512 threads (8 waves). Group g (8 WGs) owns batch rows
// [32g,32g+32). WG j owns cols [128j,128j+128); wave w owns 16 cols whose
// W-slice (16x1024 bf16 = 128 VGPR) is loaded ONCE into registers.
// Per step: stage group h(t) (64KB) -> LDS, K-loop (LDS-A x reg-B MFMA),
// tanh, store 8KB slice, release-fence + flag; consumers poll + acquire.
__global__ __launch_bounds__(512, 2) void esn_kernel(
    const float* __restrict__ x, const float* __restrict__ Win,
    const unsigned short* __restrict__ wbf,
    unsigned short* __restrict__ hA, unsigned short* __restrict__ hB,
    int* __restrict__ flags) {
  extern __shared__ char hsm[];       // 64 KB: h[32][1024] bf16, row-swizzled

  const int bid = blockIdx.x;
  // group-mates share bid&7 -> same XCD under round-robin dispatch (perf only)
  const int g = (bid & 7) | (((bid >> 3) & 3) << 3);   // 0..31
  const int j = bid >> 5;                              // 0..7
  const int tid = threadIdx.x;
  const int w = tid >> 6;             // wave 0..7
  const int lane = tid & 63;
  const int l15 = lane & 15;
  const int lq = lane >> 4;           // k-octet 0..3

  const int n0 = j * CWG + w * 16;    // wave's 16-col base
  const int m0 = g * RGRP;            // group row base

  // ---- persistent W fragments: 32 x s8v = 128 VGPR ----
  s8v bw[32];
  {
    const unsigned short* wp = wbf + (size_t)(n0 + l15) * RS + lq * 8;
#pragma unroll
    for (int kk = 0; kk < 32; kk++) bw[kk] = *(const s8v*)(wp + kk * 32);
  }

  // ---- input-proj Win fragments (hi/lo split) ----
  union U8 { s8v v; unsigned short u[8]; };
  U8 b1, b2;
  {
    const float* p = Win + (n0 + l15) * NI + (lq & 1) * 8;
#pragma unroll
    for (int i = 0; i < 8; i++) {
      float f = p[i];
      unsigned short hi = f2bf(f);
      b1.u[i] = hi;
      b2.u[i] = (lq < 2) ? f2bf(f - bf2f(hi)) : (unsigned short)0;
    }
  }

  int* flag = flags + (g << 6);       // 256B-spaced per-group counters
  const int swz = (l15 & 7) << 4;
  const char* arow0 = hsm + l15 * 2048;
  const char* arow1 = hsm + (16 + l15) * 2048;
  const float* xp0 = x + (size_t)(m0 + l15) * SL * NI + (lq & 1) * 8;
  const float* xp1 = x + (size_t)(m0 + 16 + l15) * SL * NI + (lq & 1) * 8;

  for (int t = 0; t < SL; t++) {
    const unsigned short* __restrict__ hsrc = (t & 1) ? hB : hA;
    unsigned short* __restrict__ hdst = (t & 1) ? hA : hB;

    // ---- wait for all 8 producers of this group to finish step t-1 ----
    if (t > 0) {
      if (w == 0) {
        const int target = t * WPG;
        while (__hip_atomic_load(flag, __ATOMIC_RELAXED, __HIP_MEMORY_SCOPE_AGENT) < target)
          __builtin_amdgcn_s_sleep(1);
        __builtin_amdgcn_fence(__ATOMIC_ACQUIRE, "agent");   // one inv/step
      }
      __syncthreads();
    }

    // ---- x(t) loads (flag-independent, issue early) ----
    float xf0[8], xf1[8];
    {
      const float* q0 = xp0 + (size_t)t * NI;
      const float* q1 = xp1 + (size_t)t * NI;
      *(float4*)(&xf0[0]) = *(const float4*)q0;
      *(float4*)(&xf0[4]) = *(const float4*)(q0 + 4);
      *(float4*)(&xf1[0]) = *(const float4*)q1;
      *(float4*)(&xf1[4]) = *(const float4*)(q1 + 4);
    }

    // ---- stage h(t) -> LDS, swizzled (64 KB, 8 loads in flight/wave) ----
    {
      const uint4* hs4 = (const uint4*)hsrc + (size_t)g * 4096;
      uint4 v[8];
#pragma unroll
      for (int i = 0; i < 8; i++) v[i] = hs4[tid + i * 512];
#pragma unroll
      for (int i = 0; i < 8; i++) {
        const int idx = tid + i * 512;
        const int row = idx >> 7;
        const int addr = (row << 11) | (((idx & 127) << 4) ^ ((row & 7) << 4));
        *(uint4*)(hsm + addr) = v[i];
      }
    }
    __syncthreads();

    // ---- input projection (x hi/lo split, 2 MFMAs per row-tile) ----
    f4v acc0 = {0.f, 0.f, 0.f, 0.f}, acc1 = {0.f, 0.f, 0.f, 0.f};
    {
      U8 a1, a2;
#pragma unroll
      for (int i = 0; i < 8; i++) {
        float f = xf0[i];
        unsigned short hi = f2bf(f);
        a1.u[i] = (lq < 2) ? hi : f2bf(f - bf2f(hi));
        a2.u[i] = (lq < 2) ? hi : (unsigned short)0;
      }
      acc0 = __builtin_amdgcn_mfma_f32_16x16x32_bf16(a1.v, b1.v, acc0, 0, 0, 0);
      acc0 = __builtin_amdgcn_mfma_f32_16x16x32_bf16(a2.v, b2.v, acc0, 0, 0, 0);
#pragma unroll
      for (int i = 0; i < 8; i++) {
        float f = xf1[i];
        unsigned short hi = f2bf(f);
        a1.u[i] = (lq < 2) ? hi : f2bf(f - bf2f(hi));
        a2.u[i] = (lq < 2) ? hi : (unsigned short)0;
      }
      acc1 = __builtin_amdgcn_mfma_f32_16x16x32_bf16(a1.v, b1.v, acc1, 0, 0, 0);
      acc1 = __builtin_amdgcn_mfma_f32_16x16x32_bf16(a2.v, b2.v, acc1, 0, 0, 0);
    }

    // ---- K loop: h @ W^T, A from LDS, B from registers ----
#pragma unroll
    for (int kk = 0; kk < 32; kk++) {
      const int off = (kk * 64 + lq * 16) ^ swz;
      s8v a0 = *(const s8v*)(arow0 + off);
      s8v a1v = *(const s8v*)(arow1 + off);
      acc0 = __builtin_amdgcn_mfma_f32_16x16x32_bf16(a0, bw[kk], acc0, 0, 0, 0);
      acc1 = __builtin_amdgcn_mfma_f32_16x16x32_bf16(a1v, bw[kk], acc1, 0, 0, 0);
    }

    // ---- epilogue: tanh + store 8KB slice. C/D: col=l15, row=lq*4+r ----
#pragma unroll
    for (int r = 0; r < 4; r++) {
      const int row0 = m0 + lq * 4 + r;
      const int row1 = row0 + 16;
      hdst[(size_t)row0 * RS + n0 + l15] = f2bf(fast_tanh(acc0[r]));
      hdst[(size_t)row1 * RS + n0 + l15] = f2bf(fast_tanh(acc1[r]));
    }

    // ---- publish: per-wave store drain, then one release + flag add ----
    asm volatile("s_waitcnt vmcnt(0)" ::: "memory");
    __syncthreads();
    if (tid == 0) {
      __builtin_amdgcn_fence(__ATOMIC_RELEASE, "agent");   // wbl2 (small dirty set)
      __hip_atomic_fetch_add(flag, 1, __ATOMIC_RELAXED, __HIP_MEMORY_SCOPE_AGENT);
    }
  }
}

// y = h_final @ Wout^T + b  (final h is in buffer A after 4096 steps)
__global__ __launch_bounds__(256) void yout_kernel(
    const unsigned short* __restrict__ h, const float* __restrict__ Wout,
    const float* __restrict__ bias, float* __restrict__ y) {
  const int tid = threadIdx.x;
  const int b = (blockIdx.x << 4) + (tid >> 4);
  const int o = tid & 15;
  const unsigned short* hr = h + ((size_t)b << 10);
  const float* wr = Wout + (o << 10);
  float s = 0.0f;
  for (int k = 0; k < RS; k += 8) {
#pragma unroll
    for (int i = 0; i < 8; i++) s += bf2f(hr[k + i]) * wr[k + i];
  }
  y[(b << 4) + o] = s + bias[o];
}

extern "C" void kernel_launch(void* const* d_in, const int* in_sizes, int n_in,
                              void* d_out, int out_size, void* d_ws, size_t ws_size,
                              hipStream_t stream) {
  const float* x = (const float*)d_in[0];
  const float* Win = (const float*)d_in[1];
  const float* W = (const float*)d_in[2];
  const float* Wout = (const float*)d_in[3];
  const float* bias = (const float*)d_in[4];
  float* y = (float*)d_out;

  char* ws = (char*)d_ws;
  unsigned short* hA = (unsigned short*)ws;                  // 2 MB (also final h)
  unsigned short* hB = (unsigned short*)(ws + (1 << 21));    // 2 MB
  unsigned short* wbf = (unsigned short*)(ws + (2 << 21));   // 2 MB (W bf16)
  int* flags = (int*)(ws + 3 * (size_t)(1 << 21));           // 8 KB

  hipFuncSetAttribute((const void*)esn_kernel,
                      hipFuncAttributeMaxDynamicSharedMemorySize, RGRP * 2048);

  prep_kernel<<<4096, 256, 0, stream>>>(W, wbf, (uint4*)hA, flags);
  esn_kernel<<<NGRP * WPG, 512, RGRP * 2048, stream>>>(x, Win, wbf, hA, hB, flags);
  yout_kernel<<<64, 256, 0, stream>>>(hA, Wout, bias, y);
}

// Round 8
// 19534.050 us; speedup vs baseline: 12.2851x; 2.2743x over previous
//
#include <hip/hip_runtime.h>

#define RS 1024   // reservoir
#define SL 4096   // seq len
#define NB 1024   // batch
#define NI 16     // input size
#define RGRP 32   // batch rows per group
#define NGRP 32   // groups
#define WPG 8     // WGs per group (8 * 128 cols = 1024)

typedef short s8v __attribute__((ext_vector_type(8)));
typedef float f16v __attribute__((ext_vector_type(16)));
typedef unsigned int u4v __attribute__((ext_vector_type(4)));

#define WAIT_VM(N) do { asm volatile("s_waitcnt vmcnt(" #N ")" ::: "memory"); \
                        __builtin_amdgcn_sched_barrier(0); } while (0)

static __device__ __forceinline__ unsigned short f2bf(float f) {
  unsigned u = __float_as_uint(f);
  u += 0x7fffu + ((u >> 16) & 1u);          // round-to-nearest-even
  return (unsigned short)(u >> 16);
}
static __device__ __forceinline__ float bf2f(unsigned short b) {
  return __uint_as_float(((unsigned)b) << 16);
}
static __device__ __forceinline__ float fast_tanh(float a) {
  float e = __expf(2.0f * a);               // saturates correctly at +/-inf
  return 1.0f - 2.0f / (e + 1.0f);
}

// ---- L1+L2-bypassing ops (sc0 sc1): read/write at the coherent LLC ----
// ext_vector_type (not uint4 struct!) so the "v" constraint maps to a VGPR quad.
static __device__ __forceinline__ u4v ld_llc_b128(const void* p) {
  u4v d;
  asm volatile("global_load_dwordx4 %0, %1, off sc0 sc1"
               : "=v"(d) : "v"(p) : "memory");
  return d;
}
static __device__ __forceinline__ void st_llc_b128(void* p, u4v d) {
  asm volatile("global_store_dwordx4 %0, %1, off sc0 sc1"
               : : "v"(p), "v"(d) : "memory");
}

// prep: W fp32 -> bf16; zero h0 (buffer A); zero flags
__global__ __launch_bounds__(256) void prep_kernel(
    const float* __restrict__ W, unsigned short* __restrict__ wbf,
    uint4* __restrict__ hA4, int* __restrict__ flags) {
  int idx = blockIdx.x * 256 + threadIdx.x;
  if (idx < RS * RS) wbf[idx] = f2bf(W[idx]);
  if (idx < (NB * RS) / 8) hA4[idx] = make_uint4(0u, 0u, 0u, 0u);
  if (idx < NGRP * 64) flags[idx] = 0;
}

// W-register-resident recurrence; h exchanged through the LLC with sc0sc1
// write-through stores / bypass loads; round-4-proven atomic handshake.
// h layout (hx): h[c8][row][8] bf16, c8 = col/8 (16B chunk per (c8,row)).
// 256 WGs x 256 threads (4 waves). Group g = bid&31 owns batch rows
// [32g,32g+32); WG j = bid>>5 owns cols [128j,+128); wave w owns 32 cols,
// W-slice (32x1024 bf16 = 64 frags = 256 VGPR) register-resident.
__global__ __launch_bounds__(256, 1) void esn_kernel(
    const float* __restrict__ x, const float* __restrict__ Win,
    const unsigned short* __restrict__ wbf,
    unsigned short* __restrict__ hA, unsigned short* __restrict__ hB,
    int* __restrict__ flags) {
  extern __shared__ char smem[];
  char* hsm = smem;              // 64 KB: staged group h, hx order (linear)
  char* ctile = smem + 65536;    // 8 KB: 4 x (32x32 bf16) per-wave C tiles

  const int bid = blockIdx.x;
  const int g = bid & 31;        // group
  const int j = bid >> 5;        // WG-in-group 0..7
  const int tid = threadIdx.x;
  const int w = tid >> 6;        // wave 0..3
  const int lane = tid & 63;
  const int l31 = lane & 31;
  const int hi = lane >> 5;      // k-half 0..1

  const int n0 = j * 128 + w * 32;   // wave's 32-col base
  const int m0 = g * RGRP;           // group row base

  // ---- persistent W fragments: 64 x s8v = 256 VGPR (B: col=l31, k=8hi+i) ----
  s8v bw[64];
  {
    const unsigned short* wp = wbf + (size_t)(n0 + l31) * RS + hi * 8;
#pragma unroll
    for (int kk = 0; kk < 64; kk++) bw[kk] = *(const s8v*)(wp + kk * 16);
  }

  // ---- input-proj Win fragments hi/lo ----
  union U8 { s8v v; unsigned short u[8]; };
  U8 whi, wlo;
  {
    const float* p = Win + (n0 + l31) * NI + hi * 8;
#pragma unroll
    for (int i = 0; i < 8; i++) {
      float f = p[i];
      unsigned short h16 = f2bf(f);
      whi.u[i] = h16;
      wlo.u[i] = f2bf(f - bf2f(h16));
    }
  }

  int* flag = flags + g * 64;                  // 256B-spaced group counters
  const float* xrow = x + (size_t)(m0 + l31) * SL * NI + hi * 8;
  // staging: chunk idx = q*256+tid -> c8 = q*8+(tid>>5), rowloc = tid&31
  const size_t stg_base = (((size_t)(tid >> 5) * NB) + m0 + (tid & 31)) << 4;
  const char* abase = hsm + hi * 512 + l31 * 16;   // A-frag kk at +kk*1024
  char* wct = ctile + w * 2048;                // this wave's 32x32 C tile
  int dead = 0;

  for (int t = 0; t < SL; t++) {
    const char* hsrc = (const char*)((t & 1) ? hB : hA);
    char* hdst = (char*)((t & 1) ? hA : hB);

    // ---- x(t) loads (handshake-independent; fly during poll) ----
    float4 xa = *(const float4*)(xrow + (size_t)t * NI);
    float4 xb = *(const float4*)(xrow + (size_t)t * NI + 4);

    // ---- proven handshake: counter >= t*WPG (one poller + barrier) ----
    if (t > 0) {
      if (tid == 0 && !dead) {
        const int target = t * WPG;
        int spins = 0;
        while (__hip_atomic_load(flag, __ATOMIC_RELAXED, __HIP_MEMORY_SCOPE_AGENT) < target) {
          __builtin_amdgcn_s_sleep(8);
          if (++spins > (1 << 16)) { dead = 1; break; }   // sticky watchdog:
        }                                                 // degrade, never hang
      }
      __syncthreads();
    }

    // ---- stage group h(t): 64 KB, LLC-bypass loads, linear LDS writes ----
    {
      u4v stg[16];
#pragma unroll
      for (int q = 0; q < 16; q++)
        stg[q] = ld_llc_b128(hsrc + stg_base + (size_t)q * 131072);
      WAIT_VM(8);
#pragma unroll
      for (int q = 0; q < 8; q++)
        *(u4v*)(hsm + (tid << 4) + q * 4096) = stg[q];
      WAIT_VM(0);
#pragma unroll
      for (int q = 8; q < 16; q++)
        *(u4v*)(hsm + (tid << 4) + q * 4096) = stg[q];
    }

    // ---- x fragments hi/lo (A: row=l31, k=8hi+i) ----
    U8 xhi, xlo;
    {
      float xf[8] = {xa.x, xa.y, xa.z, xa.w, xb.x, xb.y, xb.z, xb.w};
#pragma unroll
      for (int i = 0; i < 8; i++) {
        unsigned short h16 = f2bf(xf[i]);
        xhi.u[i] = h16;
        xlo.u[i] = f2bf(xf[i] - bf2f(h16));
      }
    }
    __syncthreads();    // staged h visible to all waves

    // ---- input projection: 3 MFMAs (~fp32 accuracy) ----
    f16v acc = {};
    acc = __builtin_amdgcn_mfma_f32_32x32x16_bf16(xhi.v, whi.v, acc, 0, 0, 0);
    acc = __builtin_amdgcn_mfma_f32_32x32x16_bf16(xlo.v, whi.v, acc, 0, 0, 0);
    acc = __builtin_amdgcn_mfma_f32_32x32x16_bf16(xhi.v, wlo.v, acc, 0, 0, 0);

    // ---- K loop: 64 x (conflict-free ds_read_b128 + 32x32x16 MFMA) ----
#pragma unroll
    for (int kk = 0; kk < 64; kk++) {
      s8v a = *(const s8v*)(abase + kk * 1024);
      acc = __builtin_amdgcn_mfma_f32_32x32x16_bf16(a, bw[kk], acc, 0, 0, 0);
    }

    // ---- tanh -> bf16 -> per-wave LDS C-tile (row=(r&3)+8(r>>2)+4hi, col=l31) ----
#pragma unroll
    for (int r = 0; r < 16; r++) {
      const int row = (r & 3) + 8 * (r >> 2) + 4 * hi;
      *(unsigned short*)(wct + row * 64 + l31 * 2) = f2bf(fast_tanh(acc[r]));
    }
    asm volatile("s_waitcnt lgkmcnt(0)" ::: "memory");   // wave-local transpose
    __builtin_amdgcn_sched_barrier(0);
    // ---- transpose-read C tile -> hx-layout LLC stores (coalesced) ----
    {
      const int row = lane >> 1, c = lane & 1;
      u4v v0 = *(const u4v*)(wct + row * 64 + c * 16);
      u4v v1 = *(const u4v*)(wct + row * 64 + c * 16 + 32);
      char* g0 = hdst + ((((size_t)(n0 >> 3) + c) * NB + m0 + row) << 4);
      char* g1 = hdst + ((((size_t)(n0 >> 3) + c + 2) * NB + m0 + row) << 4);
      st_llc_b128(g0, v0);
      st_llc_b128(g1, v1);
    }
    WAIT_VM(0);         // stores visible at LLC
    __syncthreads();    // all 4 waves done (and hsm reads complete)
    if (tid == 0)
      __hip_atomic_fetch_add(flag, 1, __ATOMIC_RELAXED, __HIP_MEMORY_SCOPE_AGENT);
  }
}

// y = h_final @ Wout^T + b ; h in hx layout: elem (b,k) at hx[k>>3][b][k&7]
__global__ __launch_bounds__(256) void yout_kernel(
    const unsigned short* __restrict__ h, const float* __restrict__ Wout,
    const float* __restrict__ bias, float* __restrict__ y) {
  const int tid = threadIdx.x;
  const int b = (blockIdx.x << 4) + (tid >> 4);
  const int o = tid & 15;
  const float* wr = Wout + (o << 10);
  float s = 0.0f;
  for (int k8 = 0; k8 < RS / 8; k8++) {
    const unsigned short* hc = h + (((size_t)k8 * NB + b) << 3);
#pragma unroll
    for (int i = 0; i < 8; i++) s += bf2f(hc[i]) * wr[k8 * 8 + i];
  }
  y[(b << 4) + o] = s + bias[o];
}

extern "C" void kernel_launch(void* const* d_in, const int* in_sizes, int n_in,
                              void* d_out, int out_size, void* d_ws, size_t ws_size,
                              hipStream_t stream) {
  const float* x = (const float*)d_in[0];
  const float* Win = (const float*)d_in[1];
  const float* W = (const float*)d_in[2];
  const float* Wout = (const float*)d_in[3];
  const float* bias = (const float*)d_in[4];
  float* y = (float*)d_out;

  char* ws = (char*)d_ws;
  unsigned short* hA = (unsigned short*)ws;                  // 2 MB (final h)
  unsigned short* hB = (unsigned short*)(ws + (1 << 21));    // 2 MB
  unsigned short* wbf = (unsigned short*)(ws + (2 << 21));   // 2 MB (W bf16)
  int* flags = (int*)(ws + 3 * (size_t)(1 << 21));           // 8 KB

  (void)hipFuncSetAttribute((const void*)esn_kernel,
                            hipFuncAttributeMaxDynamicSharedMemorySize, 73728);

  prep_kernel<<<4096, 256, 0, stream>>>(W, wbf, (uint4*)hA, flags);
  esn_kernel<<<NGRP * WPG, 256, 73728, stream>>>(x, Win, wbf, hA, hB, flags);
  yout_kernel<<<64, 256, 0, stream>>>(hA, Wout, bias, y);
}

// Round 9
// 17760.701 us; speedup vs baseline: 13.5117x; 1.0998x over previous
//
#include <hip/hip_runtime.h>

#define RS 1024   // reservoir
#define SL 4096   // seq len
#define NB 1024   // batch
#define NI 16     // input size
#define RGRP 32   // batch rows per group
#define NGRP 32   // groups
#define WPG 8     // WGs per group (8 * 128 cols = 1024)

typedef short s8v __attribute__((ext_vector_type(8)));
typedef float f16v __attribute__((ext_vector_type(16)));
typedef unsigned int u4v __attribute__((ext_vector_type(4)));

#define WAIT_VM(N) do { asm volatile("s_waitcnt vmcnt(" #N ")" ::: "memory"); \
                        __builtin_amdgcn_sched_barrier(0); } while (0)

static __device__ __forceinline__ unsigned short f2bf(float f) {
  unsigned u = __float_as_uint(f);
  u += 0x7fffu + ((u >> 16) & 1u);          // round-to-nearest-even
  return (unsigned short)(u >> 16);
}
static __device__ __forceinline__ float bf2f(unsigned short b) {
  return __uint_as_float(((unsigned)b) << 16);
}
static __device__ __forceinline__ float fast_tanh(float a) {
  float e = __expf(2.0f * a);               // saturates correctly at +/-inf
  return 1.0f - 2.0f / (e + 1.0f);
}

// ---- L1+L2-bypassing ops (sc0 sc1): read/write at the coherent LLC ----
static __device__ __forceinline__ u4v ld_llc_b128(const void* p) {
  u4v d;
  asm volatile("global_load_dwordx4 %0, %1, off sc0 sc1"
               : "=v"(d) : "v"(p) : "memory");
  return d;
}
static __device__ __forceinline__ void st_llc_b128(void* p, u4v d) {
  asm volatile("global_store_dwordx4 %0, %1, off sc0 sc1"
               : : "v"(p), "v"(d) : "memory");
}

// prep: W fp32 -> bf16; zero h0 (buffer A); zero flags
__global__ __launch_bounds__(256) void prep_kernel(
    const float* __restrict__ W, unsigned short* __restrict__ wbf,
    uint4* __restrict__ hA4, int* __restrict__ flags) {
  int idx = blockIdx.x * 256 + threadIdx.x;
  if (idx < RS * RS) wbf[idx] = f2bf(W[idx]);
  if (idx < (NB * RS) / 8) hA4[idx] = make_uint4(0u, 0u, 0u, 0u);
  if (idx < NGRP * 64) flags[idx] = 0;
}

// K-split W-register-resident recurrence; fence-free LLC h-exchange.
// h layout (hx): h[c8][row][8] bf16, c8 = col/8 (16B chunk per (c8,row)).
// 256 WGs x 256 threads (4 waves). Group g = bid&31 owns rows [32g,+32);
// WG j = bid>>5 owns cols [128j,+128). Wave w takes K-quarter [256w,+256)
// for ALL 128 cols (B = 4 tiles x 16 frags = 256 regs, register-resident);
// A-frags loaded DIRECTLY from global hx (no LDS staging, counted vmcnt);
// cross-wave f32 partial reduce in LDS; wave w owns+stores col-tile w.
__global__ __launch_bounds__(256, 1) void esn_kernel(
    const float* __restrict__ x, const float* __restrict__ Win,
    const unsigned short* __restrict__ wbf,
    unsigned short* __restrict__ hA, unsigned short* __restrict__ hB,
    int* __restrict__ flags) {
  extern __shared__ char smem[];
  char* psm = smem;              // 64 KB: 16 partial slots [tile c][producer w] 4KB
  char* ctile = smem + 65536;    // 8 KB: 4 x (32x32 bf16) per-wave C tiles

  const int bid = blockIdx.x;
  const int g = bid & 31;        // group
  const int j = bid >> 5;        // WG-in-group 0..7
  const int tid = threadIdx.x;
  const int w = tid >> 6;        // wave 0..3 = K-quarter, owns col-tile w
  const int lane = tid & 63;
  const int l31 = lane & 31;
  const int hi = lane >> 5;      // k-half 0..1

  const int n0 = j * 128 + w * 32;   // wave's OWN 32-col base (tile w)
  const int m0 = g * RGRP;           // group row base

  // ---- persistent W fragments: 4 tiles x 16 kk = 256 regs.
  // idx order: tile c = (w+idx)&3, so bw[0] is the OWN tile (static indices).
  s8v bw[4][16];
#pragma unroll
  for (int idx = 0; idx < 4; idx++) {
    const int c = (w + idx) & 3;
    const unsigned short* wp =
        wbf + (size_t)(j * 128 + c * 32 + l31) * RS + w * 256 + hi * 8;
#pragma unroll
    for (int kk = 0; kk < 16; kk++) bw[idx][kk] = *(const s8v*)(wp + kk * 16);
  }

  // ---- input-proj Win fragments hi/lo for OWN tile cols ----
  union U8 { s8v v; unsigned short u[8]; };
  U8 whi, wlo;
  {
    const float* p = Win + (n0 + l31) * NI + hi * 8;
#pragma unroll
    for (int i = 0; i < 8; i++) {
      float f = p[i];
      unsigned short h16 = f2bf(f);
      whi.u[i] = h16;
      wlo.u[i] = f2bf(f - bf2f(h16));
    }
  }

  int* flag = flags + g * 64;                  // 256B-spaced group counters
  const float* xrow = x + (size_t)(m0 + l31) * SL * NI + hi * 8;
  // A-frag global base: c8 = 32w + 2kk + hi, row = m0 + l31
  const size_t ab_off = (((size_t)(32 * w + hi) * NB) + m0 + l31) << 4;
  char* wct = ctile + w * 2048;                // this wave's 32x32 C tile
  int dead = 0;

  for (int t = 0; t < SL; t++) {
    const char* hsrc = (const char*)((t & 1) ? hB : hA);
    char* hdst = (char*)((t & 1) ? hA : hB);

    // ---- x(t) loads (handshake-independent; fly during poll) ----
    float4 xa = *(const float4*)(xrow + (size_t)t * NI);
    float4 xb = *(const float4*)(xrow + (size_t)t * NI + 4);

    // ---- proven handshake: counter >= t*WPG (one poller + barrier) ----
    if (t > 0) {
      if (tid == 0 && !dead) {
        const int target = t * WPG;
        int spins = 0;
        while (__hip_atomic_load(flag, __ATOMIC_RELAXED, __HIP_MEMORY_SCOPE_AGENT) < target) {
          __builtin_amdgcn_s_sleep(8);
          if (++spins > (1 << 16)) { dead = 1; break; }   // sticky watchdog
        }
      }
      __syncthreads();
    }

    // ---- x fragments hi/lo FIRST (drain x-loads before asm A-loads) ----
    U8 xhi, xlo;
    {
      float xf[8] = {xa.x, xa.y, xa.z, xa.w, xb.x, xb.y, xb.z, xb.w};
#pragma unroll
      for (int i = 0; i < 8; i++) {
        unsigned short h16 = f2bf(xf[i]);
        xhi.u[i] = h16;
        xlo.u[i] = f2bf(xf[i] - bf2f(h16));
      }
    }
    __builtin_amdgcn_sched_barrier(0);   // pin x-prep before A-load issue

    // ---- issue all 16 direct A-frag loads (K-quarter, coalesced 16B/lane) ----
    u4v al[16];
#pragma unroll
    for (int kk = 0; kk < 16; kk++)
      al[kk] = ld_llc_b128(hsrc + ab_off + (size_t)kk * (2 * NB * 16));

    // ---- input projection into OWN-tile acc (overlaps A-load flight) ----
    f16v acc[4];
    {
      f16v z = {};
      z = __builtin_amdgcn_mfma_f32_32x32x16_bf16(xhi.v, whi.v, z, 0, 0, 0);
      z = __builtin_amdgcn_mfma_f32_32x32x16_bf16(xlo.v, whi.v, z, 0, 0, 0);
      acc[0] = __builtin_amdgcn_mfma_f32_32x32x16_bf16(xhi.v, wlo.v, z, 0, 0, 0);
      f16v zz = {};
      acc[1] = zz; acc[2] = zz; acc[3] = zz;
    }

    // ---- K-quarter MFMAs, counted-vmcnt consumption (4 frags per wait) ----
#define KBLK(K0)                                                            \
    _Pragma("unroll")                                                       \
    for (int kk = K0; kk < K0 + 4; kk++) {                                  \
      union AU { u4v u; s8v s; } au; au.u = al[kk];                         \
      _Pragma("unroll")                                                     \
      for (int idx = 0; idx < 4; idx++)                                     \
        acc[idx] = __builtin_amdgcn_mfma_f32_32x32x16_bf16(au.s, bw[idx][kk], acc[idx], 0, 0, 0); \
    }
    WAIT_VM(12); KBLK(0)
    WAIT_VM(8);  KBLK(4)
    WAIT_VM(4);  KBLK(8)
    WAIT_VM(0);  KBLK(12)
#undef KBLK

    // ---- write partials for non-owned tiles to LDS (slot = tile*4 + w) ----
#pragma unroll
    for (int idx = 1; idx < 4; idx++) {
      const int c = (w + idx) & 3;
      char* slot = psm + (((c << 2) | w) << 12) + (size_t)l31 * 4;
#pragma unroll
      for (int r = 0; r < 16; r++)
        *(float*)(slot + (hi * 16 + r) * 128) = acc[idx][r];
    }
    __syncthreads();   // all partials visible

    // ---- reduce own tile: acc[0] + 3 partials from LDS ----
    f16v own = acc[0];
#pragma unroll
    for (int idx = 1; idx < 4; idx++) {
      const int wp = (w + idx) & 3;    // producer wave
      const char* slot = psm + (((w << 2) | wp) << 12) + (size_t)l31 * 4;
#pragma unroll
      for (int r = 0; r < 16; r++)
        own[r] += *(const float*)(slot + (hi * 16 + r) * 128);
    }

    // ---- tanh -> bf16 -> per-wave LDS C-tile (row=(r&3)+8(r>>2)+4hi, col=l31) ----
#pragma unroll
    for (int r = 0; r < 16; r++) {
      const int row = (r & 3) + 8 * (r >> 2) + 4 * hi;
      *(unsigned short*)(wct + row * 64 + l31 * 2) = f2bf(fast_tanh(own[r]));
    }
    asm volatile("s_waitcnt lgkmcnt(0)" ::: "memory");   // wave-local transpose
    __builtin_amdgcn_sched_barrier(0);
    // ---- transpose-read C tile -> hx-layout LLC stores (coalesced) ----
    {
      const int row = lane >> 1, c = lane & 1;
      u4v v0 = *(const u4v*)(wct + row * 64 + c * 16);
      u4v v1 = *(const u4v*)(wct + row * 64 + c * 16 + 32);
      char* g0 = hdst + ((((size_t)(n0 >> 3) + c) * NB + m0 + row) << 4);
      char* g1 = hdst + ((((size_t)(n0 >> 3) + c + 2) * NB + m0 + row) << 4);
      st_llc_b128(g0, v0);
      st_llc_b128(g1, v1);
    }
    WAIT_VM(0);         // stores visible at LLC
    __syncthreads();    // all 4 waves done (partial-slot reads complete too)
    if (tid == 0)
      __hip_atomic_fetch_add(flag, 1, __ATOMIC_RELAXED, __HIP_MEMORY_SCOPE_AGENT);
  }
}

// y = h_final @ Wout^T + b ; h in hx layout: elem (b,k) at hx[k>>3][b][k&7]
__global__ __launch_bounds__(256) void yout_kernel(
    const unsigned short* __restrict__ h, const float* __restrict__ Wout,
    const float* __restrict__ bias, float* __restrict__ y) {
  const int tid = threadIdx.x;
  const int b = (blockIdx.x << 4) + (tid >> 4);
  const int o = tid & 15;
  const float* wr = Wout + (o << 10);
  float s = 0.0f;
  for (int k8 = 0; k8 < RS / 8; k8++) {
    const unsigned short* hc = h + (((size_t)k8 * NB + b) << 3);
#pragma unroll
    for (int i = 0; i < 8; i++) s += bf2f(hc[i]) * wr[k8 * 8 + i];
  }
  y[(b << 4) + o] = s + bias[o];
}

extern "C" void kernel_launch(void* const* d_in, const int* in_sizes, int n_in,
                              void* d_out, int out_size, void* d_ws, size_t ws_size,
                              hipStream_t stream) {
  const float* x = (const float*)d_in[0];
  const float* Win = (const float*)d_in[1];
  const float* W = (const float*)d_in[2];
  const float* Wout = (const float*)d_in[3];
  const float* bias = (const float*)d_in[4];
  float* y = (float*)d_out;

  char* ws = (char*)d_ws;
  unsigned short* hA = (unsigned short*)ws;                  // 2 MB (final h)
  unsigned short* hB = (unsigned short*)(ws + (1 << 21));    // 2 MB
  unsigned short* wbf = (unsigned short*)(ws + (2 << 21));   // 2 MB (W bf16)
  int* flags = (int*)(ws + 3 * (size_t)(1 << 21));           // 8 KB

  (void)hipFuncSetAttribute((const void*)esn_kernel,
                            hipFuncAttributeMaxDynamicSharedMemorySize, 73728);

  prep_kernel<<<4096, 256, 0, stream>>>(W, wbf, (uint4*)hA, flags);
  esn_kernel<<<NGRP * WPG, 256, 73728, stream>>>(x, Win, wbf, hA, hB, flags);
  yout_kernel<<<64, 256, 0, stream>>>(hA, Wout, bias, y);
}